// Round 7
// baseline (272.523 us; speedup 1.0000x reference)
//
#include <hip/hip_runtime.h>

typedef __attribute__((ext_vector_type(4))) int i32x4;
typedef __attribute__((ext_vector_type(16))) int i32x16;
typedef unsigned short u16;
typedef unsigned char u8;
typedef unsigned int u32;
typedef unsigned long long u64;

static constexpr int NROW = 16384;   // b*h*w
static constexpr int NCODE = 8192;
static constexpr int ZN = 4194304;   // b*c*h*w
static constexpr int MARGIN_I = 4200;   // 2.5e-4 * 2^24

// Candidate row layout (256 B per row):
//   u16 slots[96]   : 16 groups (code-half*8 + wave) x 6 slots   (bytes 0..191)
//   u16 ovf[24]     : per-row spill list                          (bytes 192..239)
//   u8  counts[16]  : per-group push counts (saturated)           (bytes 240..255)
// Spill count lives in g_cnt[row]. Full-scan fallback iff g_cnt[row] > OCAP.
static constexpr int GCAP = 6;
static constexpr int OCAP = 24;

// workspace layout (bytes) — 10.6 MB
static constexpr size_t OFF_ZB8  = 0;          // i8 granules z  4 MB
static constexpr size_t OFF_EB8  = 4194304;    // i8 granules e  2 MB
static constexpr size_t OFF_CNT  = 6291456;    // int [NROW] spill counters
static constexpr size_t OFF_CAND = 6356992;    // 256 B per row  4 MB
static constexpr size_t OFF_LOSS = 10551296;   // float
static constexpr size_t OFF_CTR  = 10551300;   // int

__device__ __forceinline__ char q8(float v, float s) {
  int x = __float2int_rn(v * s);
  x = x < -128 ? -128 : (x > 127 ? 127 : x);
  return (char)x;
}

// max over each 16-lane row via DPP row_ror (VALU pipe, no LDS traffic)
__device__ __forceinline__ int rowmax16(int m) {
  m = max(m, __builtin_amdgcn_update_dpp(m, m, 0x121, 0xf, 0xf, false)); // ror:1
  m = max(m, __builtin_amdgcn_update_dpp(m, m, 0x122, 0xf, 0xf, false)); // ror:2
  m = max(m, __builtin_amdgcn_update_dpp(m, m, 0x124, 0xf, 0xf, false)); // ror:4
  m = max(m, __builtin_amdgcn_update_dpp(m, m, 0x128, 0xf, 0xf, false)); // ror:8
  return m;
}

// ---- numpy fp32 replica (verified rounds 4-9; no FMA contraction) ----
// zr must be 16B-aligned; scalars re-sourced from float4 components in the
// EXACT same operation order as the scalar version (bit-identical).
#pragma clang fp contract(off)
__device__ float np_dist(const float* zr, const float* __restrict__ er, float A) {
  const float4* e4 = (const float4*)er;
  const float4* z4 = (const float4*)zr;
  float s0 = 0.f, s1 = 0.f, s2 = 0.f, s3 = 0.f;
#pragma unroll 4
  for (int i16 = 0; i16 < 16; ++i16) {
    float4 ea = e4[i16 * 4 + 0], eb = e4[i16 * 4 + 1];
    float4 ec = e4[i16 * 4 + 2], ed = e4[i16 * 4 + 3];
    float4 za = z4[i16 * 4 + 0], zb = z4[i16 * 4 + 1];
    float4 zc = z4[i16 * 4 + 2], zd = z4[i16 * 4 + 3];
    s0 = __fadd_rn(__fmul_rn(za.x, ea.x),
         __fadd_rn(__fmul_rn(zb.x, eb.x),
         __fadd_rn(__fmul_rn(zc.x, ec.x),
         __fadd_rn(__fmul_rn(zd.x, ed.x), s0))));
    s1 = __fadd_rn(__fmul_rn(za.y, ea.y),
         __fadd_rn(__fmul_rn(zb.y, eb.y),
         __fadd_rn(__fmul_rn(zc.y, ec.y),
         __fadd_rn(__fmul_rn(zd.y, ed.y), s1))));
    s2 = __fadd_rn(__fmul_rn(za.z, ea.z),
         __fadd_rn(__fmul_rn(zb.z, eb.z),
         __fadd_rn(__fmul_rn(zc.z, ec.z),
         __fadd_rn(__fmul_rn(zd.z, ed.z), s2))));
    s3 = __fadd_rn(__fmul_rn(za.w, ea.w),
         __fadd_rn(__fmul_rn(zb.w, eb.w),
         __fadd_rn(__fmul_rn(zc.w, ec.w),
         __fadd_rn(__fmul_rn(zd.w, ed.w), s3))));
  }
  float C = __fadd_rn(__fadd_rn(s0, s1), __fadd_rn(s2, s3));
  return __fadd_rn(A, -(2.0f * C));
}

// A = np pairwise-sum replica of ||z||^2 (verified rounds 4-9).
__device__ float np_rowA(const float* zrow, int lane, volatile float* red) {
  if (lane < 16) {
    const int half = lane >> 3, jj = lane & 7;
    const float* p = zrow + half * 128 + jj;
    float acc = __fmul_rn(p[0], p[0]);
    for (int i = 8; i < 128; i += 8) acc = __fadd_rn(acc, __fmul_rn(p[i], p[i]));
    red[lane] = acc;
  }
  float h0 = __fadd_rn(__fadd_rn(__fadd_rn(red[0], red[1]), __fadd_rn(red[2], red[3])),
                       __fadd_rn(__fadd_rn(red[4], red[5]), __fadd_rn(red[6], red[7])));
  float h1 = __fadd_rn(__fadd_rn(__fadd_rn(red[8], red[9]), __fadd_rn(red[10], red[11])),
                       __fadd_rn(__fadd_rn(red[12], red[13]), __fadd_rn(red[14], red[15])));
  return __fadd_rn(h0, h1);
}
#pragma clang fp contract(fast)

// ---- kernel 1: prep — z,e -> i8 granules in 32-wide MFMA tile order ----
// 32x32x32 fragment layout: item = lane&31, k = kf*32 + (lane>>5)*16 + j.
// granule g (0..511) of a tile: kf = g>>6, lane = g&63; stored at tile*8192+g*16.
__global__ __launch_bounds__(256) void prep_kernel(const float* __restrict__ z,
                                                   const float* __restrict__ e,
                                                   char* __restrict__ zb8,
                                                   char* __restrict__ eb8,
                                                   int* __restrict__ g_cnt,
                                                   float* __restrict__ loss_ws,
                                                   int* __restrict__ ctr) {
  const int blk = blockIdx.x;
  if (blk < 512) {
    __shared__ float t[256][33];
    const int b = blk >> 5, h = blk & 31;
    const int w = threadIdx.x & 31, cc = threadIdx.x >> 5;
    const float* src = z + (size_t)b * 262144 + h * 32 + w;
#pragma unroll
    for (int c0 = 0; c0 < 256; c0 += 8) t[c0 + cc][w] = src[(size_t)(c0 + cc) * 1024];
    if (threadIdx.x < 32) g_cnt[blk * 32 + threadIdx.x] = 0;
    if (blk == 0 && threadIdx.x == 0) { *loss_ws = 0.f; *ctr = 0; }
    __syncthreads();
#pragma unroll
    for (int gi = 0; gi < 2; ++gi) {
      const int g = gi * 256 + threadIdx.x;
      const int kf = g >> 6, lane = g & 63;
      const int w2 = lane & 31, hi = lane >> 5;
      const int k0 = kf * 32 + hi * 16;
      union { char c[16]; i32x4 v; } u;
#pragma unroll
      for (int j = 0; j < 16; ++j) u.c[j] = q8(t[k0 + j][w2], 16.0f);
      *(i32x4*)(zb8 + (size_t)blk * 8192 + (size_t)g * 16) = u.v;
    }
  } else {
    const int G = (blk - 512) * 256 + threadIdx.x;   // 0..131071
    const int lane = G & 63, kf = (G >> 6) & 7, ct = G >> 9;
    const int code = ct * 32 + (lane & 31);
    const int k0 = kf * 32 + (lane >> 5) * 16;
    const float* s = e + (size_t)code * 256 + k0;
    union { char c[16]; i32x4 v; } u;
#pragma unroll
    for (int j = 0; j < 16; ++j) u.c[j] = q8(s[j], 1048576.0f);
    *(i32x4*)(eb8 + (size_t)G * 16) = u.v;
  }
}

// ---- kernel 2: streaming i8 MFMA scores (32x32x32) ----
// 32k MACs/inst -> 144 MFMA/wave (was 288), 16 chunks of 256 codes (was 32x128).
// Frozen thresholds: thr[] = s_rm - MARGIN recomputed only at syncs (stale thr
// <= final_max - MARGIN -> push set stays a superset; s_rm is monotone).
__global__ __launch_bounds__(512, 2) void scores_kernel(const char* __restrict__ zb8,
                                                        const char* __restrict__ eb8,
                                                        int* __restrict__ g_cnt,
                                                        char* __restrict__ cand) {
  __shared__ int s_rm[32];
  __shared__ u32 s_cnt[32][8];
  const int tid = threadIdx.x;
  const int wave = tid >> 6, lane = tid & 63;
  const int l31 = lane & 31, hi = lane >> 5;
  const int row0 = (int)(blockIdx.x >> 1) * 32;
  const int half = (int)(blockIdx.x & 1);
  const int code0 = half * 4096;
  const int grp = half * 8 + wave;
  u16* cand16 = (u16*)cand;
  if (tid < 32) s_rm[tid] = INT_MIN;
  if (tid < 256) s_cnt[tid >> 3][tid & 7] = 0;

  i32x4 a[8];
  {
    const i32x4* ab = (const i32x4*)(zb8 + (size_t)(blockIdx.x >> 1) * 8192);
#pragma unroll
    for (int kf = 0; kf < 8; ++kf) a[kf] = ab[kf * 64 + lane];
  }
  __syncthreads();   // s_rm/s_cnt init visible

  const i32x4* ebase = (const i32x4*)eb8 + (size_t)(code0 >> 5) * 512;
  int lmax[16], thr[16];

#define COMPUTE(CH, ACC)                                                          \
  i32x16 ACC = {0,0,0,0,0,0,0,0,0,0,0,0,0,0,0,0};                                 \
  {                                                                               \
    const i32x4* bt = ebase + (size_t)((CH) * 8 + wave) * 512;                    \
    i32x4 b0 = bt[lane], b1 = bt[64 + lane], b2 = bt[128 + lane], b3 = bt[192 + lane]; \
    ACC = __builtin_amdgcn_mfma_i32_32x32x32_i8(a[0], b0, ACC, 0, 0, 0);          \
    ACC = __builtin_amdgcn_mfma_i32_32x32x32_i8(a[1], b1, ACC, 0, 0, 0);          \
    ACC = __builtin_amdgcn_mfma_i32_32x32x32_i8(a[2], b2, ACC, 0, 0, 0);          \
    ACC = __builtin_amdgcn_mfma_i32_32x32x32_i8(a[3], b3, ACC, 0, 0, 0);          \
    i32x4 b4 = bt[256 + lane], b5 = bt[320 + lane], b6 = bt[384 + lane], b7 = bt[448 + lane]; \
    ACC = __builtin_amdgcn_mfma_i32_32x32x32_i8(a[4], b4, ACC, 0, 0, 0);          \
    ACC = __builtin_amdgcn_mfma_i32_32x32x32_i8(a[5], b5, ACC, 0, 0, 0);          \
    ACC = __builtin_amdgcn_mfma_i32_32x32x32_i8(a[6], b6, ACC, 0, 0, 0);          \
    ACC = __builtin_amdgcn_mfma_i32_32x32x32_i8(a[7], b7, ACC, 0, 0, 0);          \
  }

// Row r's 32 values live in lanes hi*32..hi*32+31 = two 16-lane DPP rows.
// rowmax16 per 16-lane row, then lanes (lane&15)==0 (i.e. 0,16 / 32,48) both
// atomicMax the same s_rm slot — monotone merge gives the full 32-lane max.
#define SYNC_THR()                                                               \
  {                                                                              \
    _Pragma("unroll")                                                            \
    for (int reg = 0; reg < 16; ++reg) {                                         \
      const int brow = (reg & 3) + 8 * (reg >> 2);                               \
      int m = rowmax16(lmax[reg]);                                               \
      if ((lane & 15) == 0) atomicMax(&s_rm[brow + 4 * hi], m);                  \
    }                                                                            \
    asm volatile("s_waitcnt lgkmcnt(0)\n\ts_barrier" ::: "memory");              \
    _Pragma("unroll")                                                            \
    for (int reg = 0; reg < 16; ++reg) {                                         \
      const int brow = (reg & 3) + 8 * (reg >> 2);                               \
      thr[reg] = s_rm[brow + 4 * hi] - MARGIN_I;                                 \
    }                                                                            \
  }

  // seed: chunks 0..1 (512 codes), maxes only — no pushes against a cold threshold
#pragma unroll 1
  for (int ch = 0; ch < 2; ++ch) {
    COMPUTE(ch, acc);
    if (ch == 0) {
#pragma unroll
      for (int reg = 0; reg < 16; ++reg) lmax[reg] = acc[reg];
    } else {
#pragma unroll
      for (int reg = 0; reg < 16; ++reg) lmax[reg] = max(lmax[reg], acc[reg]);
    }
  }
  SYNC_THR();

#pragma unroll 1
  for (int ch = 0; ch < 16; ++ch) {
    COMPUTE(ch, acc);
#pragma unroll
    for (int reg = 0; reg < 16; ++reg) {
      const int brow = (reg & 3) + 8 * (reg >> 2);
      const int v = acc[reg];
      const bool p = v > thr[reg];                 // frozen thr: superset of final
      if (__any(p)) {                              // scalar skip: pushes are rare
        if (p) {
          const int rl = brow + 4 * hi;
          u32 q = atomicAdd(&s_cnt[rl][wave], 1u); // LDS atomic (fast path)
          if (q < GCAP) {
            cand16[(size_t)(row0 + rl) * 128 + grp * GCAP + q] =
                (u16)(code0 + ch * 256 + wave * 32 + l31);
          } else {                                 // rare spill tier
            int o = atomicAdd(&g_cnt[row0 + rl], 1);
            if (o < OCAP)
              cand16[(size_t)(row0 + rl) * 128 + 96 + o] =
                  (u16)(code0 + ch * 256 + wave * 32 + l31);
          }
        }
      }
      lmax[reg] = max(lmax[reg], v);
    }
    if ((ch & 1) == 1 && ch != 15) SYNC_THR();
  }
#undef COMPUTE
#undef SYNC_THR

  // write out per-(row,group) counts — each wave owns its groups exclusively
  __syncthreads();
  if (tid < 256) {
    const int rl = tid >> 3, w = tid & 7;
    u32 c = s_cnt[rl][w];
    cand[(size_t)(row0 + rl) * 256 + 240 + half * 8 + w] = (u8)(c > 255u ? 255u : c);
  }
}

// ---- kernel 3: pair-compacted numpy-replica rescore + z_st gather + loss ----
__global__ __launch_bounds__(512) void rescore_fin_kernel(const float* __restrict__ z,
                                                          const float* __restrict__ emb,
                                                          const int* __restrict__ g_cnt,
                                                          const char* __restrict__ cand,
                                                          float* __restrict__ loss_ws,
                                                          int* __restrict__ ctr,
                                                          float* __restrict__ z_st,
                                                          float* __restrict__ out_loss,
                                                          float* __restrict__ out_idx) {
  __shared__ float zrows[32][260];
  __shared__ float red_s[8][16];
  __shared__ float A_s[32], D_s[32];
  __shared__ u64 best_s[32];
  __shared__ int widx_s[32], starts[33], ovf_list[32], rowtot[32];
  __shared__ int nP, nOvf;
  __shared__ u8 cnts8[32][17];
  __shared__ u16 grpoff[32][17];
  __shared__ u8 prow[32 * 120];
  __shared__ u16 pidx[32 * 120];
  const int bh = blockIdx.x;
  const int b = bh >> 5, h = bh & 31;
  const int n0 = bh * 32;
  const int tid = threadIdx.x;
  const int wave = tid >> 6, lane = tid & 63;
  const u16* cand16 = (const u16*)cand;
  {
    const float* src = z + (size_t)b * 262144 + h * 32;
    const int w = tid & 31, c16 = tid >> 5;   // c16: 0..15
#pragma unroll
    for (int c0 = 0; c0 < 256; c0 += 16) {
      int c = c0 + c16;
      zrows[w][c] = src[(size_t)c * 1024 + w];
    }
  }
  if (tid < 32) best_s[tid] = ~0ull;
  __syncthreads();

  for (int j = 0; j < 4; ++j) {
    const int r = wave * 4 + j;
    float A = np_rowA(zrows[r], lane, red_s[wave]);
    if (lane == 0) A_s[r] = A;
  }
  if (tid < 32) {
    const int r = tid;
    const u32* cw = (const u32*)(cand + (size_t)(n0 + r) * 256 + 240);
    u32 wv[4] = {cw[0], cw[1], cw[2], cw[3]};
    int tot = 0;
#pragma unroll
    for (int k = 0; k < 16; ++k) {
      int c = (int)((wv[k >> 2] >> ((k & 3) * 8)) & 0xff);
      int cc = c > GCAP ? GCAP : c;
      cnts8[r][k] = (u8)cc;
      grpoff[r][k] = (u16)tot;
      tot += cc;
    }
    const int ov = g_cnt[n0 + r];
    const int oc = ov > OCAP ? OCAP : ov;
    cnts8[r][16] = (u8)oc;
    grpoff[r][16] = (u16)tot;
    tot += oc;
    rowtot[r] = (ov > OCAP) ? 0 : tot;   // 0 -> block-wide full-scan fallback
  }
  __syncthreads();
  if (tid == 0) {
    int acc = 0, no = 0;
    for (int r = 0; r < 32; ++r) {
      starts[r] = acc;
      acc += rowtot[r];
      if (rowtot[r] == 0) ovf_list[no++] = r;
    }
    starts[32] = acc; nP = acc; nOvf = no;
  }
  __syncthreads();
  {
    const int r = tid >> 4, g = tid & 15;   // 512 threads cover [32][16]
    if (rowtot[r]) {
      const int c = cnts8[r][g];
      const int base = starts[r] + grpoff[r][g];
      const int sb = g * GCAP;
      for (int j = 0; j < c; ++j) {
        prow[base + j] = (u8)r;
        pidx[base + j] = cand16[(size_t)(n0 + r) * 128 + sb + j];
      }
    }
  }
  if (tid < 32) {
    const int r = tid;
    if (rowtot[r]) {
      const int c = cnts8[r][16];
      const int base = starts[r] + grpoff[r][16];
      for (int j = 0; j < c; ++j) {
        prow[base + j] = (u8)r;
        pidx[base + j] = cand16[(size_t)(n0 + r) * 128 + 96 + j];
      }
    }
  }
  __syncthreads();

  const int P = nP;
  for (int p = tid; p < P; p += 512) {
    const int r = prow[p], idx = (int)pidx[p];
    float D = np_dist(zrows[r], emb + (size_t)idx * 256, A_s[r]);
    u64 key = ((u64)__float_as_uint(D) << 16) | (u32)idx;
    atomicMin(&best_s[r], key);
  }
  __syncthreads();

  // overflow fallback (spill>OCAP, ~never): block-wide scan
  for (int i = 0; i < nOvf; ++i) {
    const int r = ovf_list[i];
    for (int idx = tid; idx < NCODE; idx += 512) {
      float D = np_dist(zrows[r], emb + (size_t)idx * 256, A_s[r]);
      u64 k = ((u64)__float_as_uint(D) << 16) | (u32)idx;
      atomicMin(&best_s[r], k);
    }
  }
  if (nOvf) __syncthreads();

  if (tid < 32) {
    const int r = tid;
    const u64 k = best_s[r];
    const int bidx = (int)(k & 0xFFFF);
    widx_s[r] = bidx;
    out_idx[n0 + r] = (float)bidx;
    D_s[r] = __uint_as_float((u32)(k >> 16));
  }
  __syncthreads();
  if (tid == 0) {
    float s = 0.f;
    for (int r = 0; r < 32; ++r) s += D_s[r];
    atomicAdd(loss_ws, s);
    __threadfence();
    int t = atomicAdd(ctr, 1);
    if (t == 511)
      *out_loss = atomicAdd(loss_ws, 0.0f) * (1.25f / 4194304.0f);
  }

  {
    const int col = tid & 255, hi = tid >> 8;
#pragma unroll
    for (int wi0 = 0; wi0 < 16; ++wi0) {
      const int wi = wi0 * 2 + hi;
      zrows[wi][col] = emb[(size_t)widx_s[wi] * 256 + col];
    }
  }
  __syncthreads();
  {
    const int w = tid & 31, c0 = (tid >> 5) & 7, hi = tid >> 8;
    float* dst = z_st + (size_t)b * 262144 + h * 32 + w;
#pragma unroll
    for (int cj = 0; cj < 16; ++cj) {
      int c = c0 + (cj * 2 + hi) * 8;
      dst[(size_t)c * 1024] = zrows[w][c];
    }
  }
}

extern "C" void kernel_launch(void* const* d_in, const int* in_sizes, int n_in,
                              void* d_out, int out_size, void* d_ws, size_t ws_size,
                              hipStream_t stream) {
  const float* z = (const float*)d_in[0];     // fp32 [16,256,32,32]
  const float* emb = (const float*)d_in[1];   // fp32 [8192,256]
  char* ws = (char*)d_ws;
  char* zb8 = ws + OFF_ZB8;
  char* eb8 = ws + OFF_EB8;
  int* g_cnt = (int*)(ws + OFF_CNT);
  char* cand = ws + OFF_CAND;
  float* loss_ws = (float*)(ws + OFF_LOSS);
  int* ctr = (int*)(ws + OFF_CTR);
  float* out = (float*)d_out;
  float* out_loss = out + ZN;       // output 1
  float* out_idx = out + ZN + 1;    // output 2

  prep_kernel<<<1024, 256, 0, stream>>>(z, emb, zb8, eb8, g_cnt, loss_ws, ctr);
  scores_kernel<<<1024, 512, 0, stream>>>(zb8, eb8, g_cnt, cand);
  rescore_fin_kernel<<<512, 512, 0, stream>>>(z, emb, g_cnt, cand, loss_ws, ctr,
                                              out, out_loss, out_idx);
}

// Round 8
// 217.060 us; speedup vs baseline: 1.2555x; 1.2555x over previous
//
#include <hip/hip_runtime.h>

typedef __attribute__((ext_vector_type(4))) int i32x4;
typedef unsigned short u16;
typedef unsigned char u8;
typedef unsigned int u32;
typedef unsigned long long u64;

static constexpr int NROW = 16384;   // b*h*w
static constexpr int NCODE = 8192;
static constexpr int ZN = 4194304;   // b*c*h*w
static constexpr int MARGIN_I = 4200;   // 2.5e-4 * 2^24

// Candidate row layout (256 B per row):
//   u16 slots[96]   : 16 groups (code-half*8 + wave) x 6 slots   (bytes 0..191)
//   u16 ovf[24]     : per-row spill list                          (bytes 192..239)
//   u8  counts[16]  : per-group push counts (saturated)           (bytes 240..255)
// Spill count lives in g_cnt[row]. Full-scan fallback iff g_cnt[row] > OCAP.
static constexpr int GCAP = 6;
static constexpr int OCAP = 24;

// workspace layout (bytes) — 10.6 MB
static constexpr size_t OFF_ZB8  = 0;          // i8 granules z  4 MB
static constexpr size_t OFF_EB8  = 4194304;    // i8 granules e  2 MB
static constexpr size_t OFF_CNT  = 6291456;    // int [NROW] spill counters
static constexpr size_t OFF_CAND = 6356992;    // 256 B per row  4 MB
static constexpr size_t OFF_LOSS = 10551296;   // float
static constexpr size_t OFF_CTR  = 10551300;   // int

__device__ __forceinline__ char q8(float v, float s) {
  int x = __float2int_rn(v * s);
  x = x < -128 ? -128 : (x > 127 ? 127 : x);
  return (char)x;
}

// max over each 16-lane row via DPP row_ror (VALU pipe, no LDS traffic)
__device__ __forceinline__ int rowmax16(int m) {
  m = max(m, __builtin_amdgcn_update_dpp(m, m, 0x121, 0xf, 0xf, false)); // ror:1
  m = max(m, __builtin_amdgcn_update_dpp(m, m, 0x122, 0xf, 0xf, false)); // ror:2
  m = max(m, __builtin_amdgcn_update_dpp(m, m, 0x124, 0xf, 0xf, false)); // ror:4
  m = max(m, __builtin_amdgcn_update_dpp(m, m, 0x128, 0xf, 0xf, false)); // ror:8
  return m;
}

// ---- numpy fp32 replica (verified rounds 4-9; no FMA contraction) ----
// zr must be 16B-aligned; scalars re-sourced from float4 components in the
// EXACT same operation order as the scalar version (bit-identical).
#pragma clang fp contract(off)
__device__ float np_dist(const float* zr, const float* __restrict__ er, float A) {
  const float4* e4 = (const float4*)er;
  const float4* z4 = (const float4*)zr;
  float s0 = 0.f, s1 = 0.f, s2 = 0.f, s3 = 0.f;
#pragma unroll 4
  for (int i16 = 0; i16 < 16; ++i16) {
    float4 ea = e4[i16 * 4 + 0], eb = e4[i16 * 4 + 1];
    float4 ec = e4[i16 * 4 + 2], ed = e4[i16 * 4 + 3];
    float4 za = z4[i16 * 4 + 0], zb = z4[i16 * 4 + 1];
    float4 zc = z4[i16 * 4 + 2], zd = z4[i16 * 4 + 3];
    s0 = __fadd_rn(__fmul_rn(za.x, ea.x),
         __fadd_rn(__fmul_rn(zb.x, eb.x),
         __fadd_rn(__fmul_rn(zc.x, ec.x),
         __fadd_rn(__fmul_rn(zd.x, ed.x), s0))));
    s1 = __fadd_rn(__fmul_rn(za.y, ea.y),
         __fadd_rn(__fmul_rn(zb.y, eb.y),
         __fadd_rn(__fmul_rn(zc.y, ec.y),
         __fadd_rn(__fmul_rn(zd.y, ed.y), s1))));
    s2 = __fadd_rn(__fmul_rn(za.z, ea.z),
         __fadd_rn(__fmul_rn(zb.z, eb.z),
         __fadd_rn(__fmul_rn(zc.z, ec.z),
         __fadd_rn(__fmul_rn(zd.z, ed.z), s2))));
    s3 = __fadd_rn(__fmul_rn(za.w, ea.w),
         __fadd_rn(__fmul_rn(zb.w, eb.w),
         __fadd_rn(__fmul_rn(zc.w, ec.w),
         __fadd_rn(__fmul_rn(zd.w, ed.w), s3))));
  }
  float C = __fadd_rn(__fadd_rn(s0, s1), __fadd_rn(s2, s3));
  return __fadd_rn(A, -(2.0f * C));
}

// A = np pairwise-sum replica of ||z||^2 (verified rounds 4-9).
__device__ float np_rowA(const float* zrow, int lane, volatile float* red) {
  if (lane < 16) {
    const int half = lane >> 3, jj = lane & 7;
    const float* p = zrow + half * 128 + jj;
    float acc = __fmul_rn(p[0], p[0]);
    for (int i = 8; i < 128; i += 8) acc = __fadd_rn(acc, __fmul_rn(p[i], p[i]));
    red[lane] = acc;
  }
  float h0 = __fadd_rn(__fadd_rn(__fadd_rn(red[0], red[1]), __fadd_rn(red[2], red[3])),
                       __fadd_rn(__fadd_rn(red[4], red[5]), __fadd_rn(red[6], red[7])));
  float h1 = __fadd_rn(__fadd_rn(__fadd_rn(red[8], red[9]), __fadd_rn(red[10], red[11])),
                       __fadd_rn(__fadd_rn(red[12], red[13]), __fadd_rn(red[14], red[15])));
  return __fadd_rn(h0, h1);
}
#pragma clang fp contract(fast)

// ---- kernel 1: prep — z,e -> i8 lane-ordered granules; zero cnt/loss/ctr ----
__global__ __launch_bounds__(256) void prep_kernel(const float* __restrict__ z,
                                                   const float* __restrict__ e,
                                                   char* __restrict__ zb8,
                                                   char* __restrict__ eb8,
                                                   int* __restrict__ g_cnt,
                                                   float* __restrict__ loss_ws,
                                                   int* __restrict__ ctr) {
  const int blk = blockIdx.x;
  if (blk < 512) {
    __shared__ float t[256][33];
    const int b = blk >> 5, h = blk & 31;
    const int w = threadIdx.x & 31, cc = threadIdx.x >> 5;
    const float* src = z + (size_t)b * 262144 + h * 32 + w;
#pragma unroll
    for (int c0 = 0; c0 < 256; c0 += 8) t[c0 + cc][w] = src[(size_t)(c0 + cc) * 1024];
    if (threadIdx.x < 32) g_cnt[blk * 32 + threadIdx.x] = 0;
    if (blk == 0 && threadIdx.x == 0) { *loss_ws = 0.f; *ctr = 0; }
    __syncthreads();
#pragma unroll
    for (int gi = 0; gi < 2; ++gi) {
      const int g = gi * 256 + threadIdx.x;
      const int kb = g >> 7, l4 = (g >> 5) & 3, w2 = g & 31;
      const int c0 = kb * 64 + l4 * 16;
      union { char c[16]; i32x4 v; } u;
#pragma unroll
      for (int j = 0; j < 16; ++j) u.c[j] = q8(t[c0 + j][w2], 16.0f);
      const int tile = blk * 2 + (w2 >> 4);
      *(i32x4*)(zb8 + (size_t)tile * 4096 + (size_t)(kb * 64 + l4 * 16 + (w2 & 15)) * 16) = u.v;
    }
  } else {
    const int G = (blk - 512) * 256 + threadIdx.x;
    const int tile = G >> 8, r = G & 255;
    const int kb = r >> 6, lane = r & 63;
    const int l4 = lane >> 4, l15 = lane & 15;
    const float* s = e + (size_t)(tile * 16 + l15) * 256 + kb * 64 + l4 * 16;
    union { char c[16]; i32x4 v; } u;
#pragma unroll
    for (int j = 0; j < 16; ++j) u.c[j] = q8(s[j], 1048576.0f);
    *(i32x4*)(eb8 + (size_t)G * 16) = u.v;
  }
}

// ---- kernel 2: streaming i8 MFMA scores (round-6 structure, 16x16x64) ----
// Round-7 lesson: 32x32x32 halves instr count but serializes 8 dependent MFMAs
// into one acc chain and fattens waves -> MfmaUtil DROPPED. Reverted.
// Change vs round 6: launch_bounds(512,4). Round-6 compiled to 52 VGPR, which
// fits the 64-reg budget -> 4 blocks/CU = 32 waves/CU (2x occupancy).
// Tripwire: WRITE_SIZE must stay ~3.7 MB (>10 MB means spill -> revert).
__global__ __launch_bounds__(512, 4) void scores_kernel(const char* __restrict__ zb8,
                                                        const char* __restrict__ eb8,
                                                        int* __restrict__ g_cnt,
                                                        char* __restrict__ cand) {
  __shared__ int s_rm[32];
  __shared__ u32 s_cnt[32][8];
  const int tid = threadIdx.x;
  const int wave = tid >> 6, lane = tid & 63;
  const int l15 = lane & 15, l4 = lane >> 4;
  const int row0 = (int)(blockIdx.x >> 1) * 32;
  const int half = (int)(blockIdx.x & 1);
  const int code0 = half * 4096;
  const int grp = half * 8 + wave;
  u16* cand16 = (u16*)cand;
  if (tid < 32) s_rm[tid] = INT_MIN;
  if (tid < 256) s_cnt[tid >> 3][tid & 7] = 0;

  i32x4 a[2][4];
#pragma unroll
  for (int rt = 0; rt < 2; ++rt) {
    const i32x4* ab = (const i32x4*)(zb8 + (size_t)((row0 >> 4) + rt) * 4096);
#pragma unroll
    for (int kb = 0; kb < 4; ++kb) a[rt][kb] = ab[kb * 64 + lane];
  }
  __syncthreads();   // s_rm/s_cnt init visible

  const i32x4* ebase = (const i32x4*)eb8 + (size_t)(code0 >> 4) * 256;
  int lmax[2][4];

#define COMPUTE(CH, ACC)                                                          \
  i32x4 ACC[2] = {{0,0,0,0},{0,0,0,0}};                                           \
  {                                                                               \
    const i32x4* bt = ebase + (size_t)((CH) * 8 + wave) * 256;                    \
    i32x4 bf0 = bt[lane], bf1 = bt[64 + lane], bf2 = bt[128 + lane], bf3 = bt[192 + lane]; \
    _Pragma("unroll")                                                             \
    for (int rt = 0; rt < 2; ++rt) {                                              \
      ACC[rt] = __builtin_amdgcn_mfma_i32_16x16x64_i8(a[rt][0], bf0, ACC[rt], 0, 0, 0); \
      ACC[rt] = __builtin_amdgcn_mfma_i32_16x16x64_i8(a[rt][1], bf1, ACC[rt], 0, 0, 0); \
      ACC[rt] = __builtin_amdgcn_mfma_i32_16x16x64_i8(a[rt][2], bf2, ACC[rt], 0, 0, 0); \
      ACC[rt] = __builtin_amdgcn_mfma_i32_16x16x64_i8(a[rt][3], bf3, ACC[rt], 0, 0, 0); \
    }                                                                             \
  }

// s_rm is monotone (atomicMax only, never reset) -> one relaxed barrier is safe;
// drain LDS only so in-flight global loads survive the barrier.
#define SYNC_THR()                                                               \
  {                                                                              \
    _Pragma("unroll")                                                            \
    for (int rt = 0; rt < 2; ++rt)                                               \
      _Pragma("unroll")                                                          \
      for (int r = 0; r < 4; ++r) {                                              \
        int m = rowmax16(lmax[rt][r]);                                           \
        if (l15 == 0) atomicMax(&s_rm[rt * 16 + l4 * 4 + r], m);                 \
      }                                                                          \
    asm volatile("s_waitcnt lgkmcnt(0)\n\ts_barrier" ::: "memory");              \
    _Pragma("unroll")                                                            \
    for (int rt = 0; rt < 2; ++rt)                                               \
      _Pragma("unroll")                                                          \
      for (int r = 0; r < 4; ++r)                                                \
        lmax[rt][r] = max(lmax[rt][r], s_rm[rt * 16 + l4 * 4 + r]);              \
  }

  // seed: chunks 0..1 (256 codes), maxes only — warms the threshold; the spill
  // tier absorbs the marginally larger push set vs a 4-chunk seed.
#pragma unroll 1
  for (int ch = 0; ch < 2; ++ch) {
    COMPUTE(ch, acc);
    if (ch == 0) {
#pragma unroll
      for (int rt = 0; rt < 2; ++rt)
#pragma unroll
        for (int r = 0; r < 4; ++r) lmax[rt][r] = acc[rt][r];
    } else {
#pragma unroll
      for (int rt = 0; rt < 2; ++rt)
#pragma unroll
        for (int r = 0; r < 4; ++r) lmax[rt][r] = max(lmax[rt][r], acc[rt][r]);
    }
  }
  SYNC_THR();

#pragma unroll 1
  for (int ch = 0; ch < 32; ++ch) {
    COMPUTE(ch, acc);
#pragma unroll
    for (int rt = 0; rt < 2; ++rt)
#pragma unroll
      for (int r = 0; r < 4; ++r) {
        const int v = acc[rt][r];
        const bool p = v > lmax[rt][r] - MARGIN_I;   // superset of final set
        if (__any(p)) {                              // scalar skip: pushes are rare
          if (p) {
            const int rl = rt * 16 + l4 * 4 + r;
            u32 q = atomicAdd(&s_cnt[rl][wave], 1u); // LDS atomic (fast path)
            if (q < GCAP) {
              cand16[(size_t)(row0 + rl) * 128 + grp * GCAP + q] =
                  (u16)(code0 + ch * 128 + wave * 16 + l15);
            } else {                                 // rare spill tier
              int o = atomicAdd(&g_cnt[row0 + rl], 1);
              if (o < OCAP)
                cand16[(size_t)(row0 + rl) * 128 + 96 + o] =
                    (u16)(code0 + ch * 128 + wave * 16 + l15);
            }
          }
        }
        lmax[rt][r] = max(lmax[rt][r], v);
      }
    if ((ch & 3) == 3 && ch != 31) SYNC_THR();
  }
#undef COMPUTE
#undef SYNC_THR

  // write out per-(row,group) counts — each wave owns its groups exclusively
  __syncthreads();
  if (tid < 256) {
    const int rl = tid >> 3, w = tid & 7;
    u32 c = s_cnt[rl][w];
    cand[(size_t)(row0 + rl) * 256 + 240 + half * 8 + w] = (u8)(c > 255u ? 255u : c);
  }
}

// ---- kernel 3: pair-compacted numpy-replica rescore + z_st gather + loss ----
// 512 threads (2x latency hiding) + float4 LDS reads in np_dist (4x fewer
// LDS instructions). zrows stride 260 floats for 16B alignment.
__global__ __launch_bounds__(512) void rescore_fin_kernel(const float* __restrict__ z,
                                                          const float* __restrict__ emb,
                                                          const int* __restrict__ g_cnt,
                                                          const char* __restrict__ cand,
                                                          float* __restrict__ loss_ws,
                                                          int* __restrict__ ctr,
                                                          float* __restrict__ z_st,
                                                          float* __restrict__ out_loss,
                                                          float* __restrict__ out_idx) {
  __shared__ float zrows[32][260];
  __shared__ float red_s[8][16];
  __shared__ float A_s[32], D_s[32];
  __shared__ u64 best_s[32];
  __shared__ int widx_s[32], starts[33], ovf_list[32], rowtot[32];
  __shared__ int nP, nOvf;
  __shared__ u8 cnts8[32][17];
  __shared__ u16 grpoff[32][17];
  __shared__ u8 prow[32 * 120];
  __shared__ u16 pidx[32 * 120];
  const int bh = blockIdx.x;
  const int b = bh >> 5, h = bh & 31;
  const int n0 = bh * 32;
  const int tid = threadIdx.x;
  const int wave = tid >> 6, lane = tid & 63;
  const u16* cand16 = (const u16*)cand;
  {
    const float* src = z + (size_t)b * 262144 + h * 32;
    const int w = tid & 31, c16 = tid >> 5;   // c16: 0..15
#pragma unroll
    for (int c0 = 0; c0 < 256; c0 += 16) {
      int c = c0 + c16;
      zrows[w][c] = src[(size_t)c * 1024 + w];
    }
  }
  if (tid < 32) best_s[tid] = ~0ull;
  __syncthreads();

  for (int j = 0; j < 4; ++j) {
    const int r = wave * 4 + j;
    float A = np_rowA(zrows[r], lane, red_s[wave]);
    if (lane == 0) A_s[r] = A;
  }
  if (tid < 32) {
    const int r = tid;
    const u32* cw = (const u32*)(cand + (size_t)(n0 + r) * 256 + 240);
    u32 wv[4] = {cw[0], cw[1], cw[2], cw[3]};
    int tot = 0;
#pragma unroll
    for (int k = 0; k < 16; ++k) {
      int c = (int)((wv[k >> 2] >> ((k & 3) * 8)) & 0xff);
      int cc = c > GCAP ? GCAP : c;
      cnts8[r][k] = (u8)cc;
      grpoff[r][k] = (u16)tot;
      tot += cc;
    }
    const int ov = g_cnt[n0 + r];
    const int oc = ov > OCAP ? OCAP : ov;
    cnts8[r][16] = (u8)oc;
    grpoff[r][16] = (u16)tot;
    tot += oc;
    rowtot[r] = (ov > OCAP) ? 0 : tot;   // 0 -> block-wide full-scan fallback
  }
  __syncthreads();
  if (tid == 0) {
    int acc = 0, no = 0;
    for (int r = 0; r < 32; ++r) {
      starts[r] = acc;
      acc += rowtot[r];
      if (rowtot[r] == 0) ovf_list[no++] = r;
    }
    starts[32] = acc; nP = acc; nOvf = no;
  }
  __syncthreads();
  {
    const int r = tid >> 4, g = tid & 15;   // 512 threads cover [32][16]
    if (rowtot[r]) {
      const int c = cnts8[r][g];
      const int base = starts[r] + grpoff[r][g];
      const int sb = g * GCAP;
      for (int j = 0; j < c; ++j) {
        prow[base + j] = (u8)r;
        pidx[base + j] = cand16[(size_t)(n0 + r) * 128 + sb + j];
      }
    }
  }
  if (tid < 32) {
    const int r = tid;
    if (rowtot[r]) {
      const int c = cnts8[r][16];
      const int base = starts[r] + grpoff[r][16];
      for (int j = 0; j < c; ++j) {
        prow[base + j] = (u8)r;
        pidx[base + j] = cand16[(size_t)(n0 + r) * 128 + 96 + j];
      }
    }
  }
  __syncthreads();

  const int P = nP;
  for (int p = tid; p < P; p += 512) {
    const int r = prow[p], idx = (int)pidx[p];
    float D = np_dist(zrows[r], emb + (size_t)idx * 256, A_s[r]);
    u64 key = ((u64)__float_as_uint(D) << 16) | (u32)idx;
    atomicMin(&best_s[r], key);
  }
  __syncthreads();

  // overflow fallback (spill>OCAP, ~never): block-wide scan
  for (int i = 0; i < nOvf; ++i) {
    const int r = ovf_list[i];
    for (int idx = tid; idx < NCODE; idx += 512) {
      float D = np_dist(zrows[r], emb + (size_t)idx * 256, A_s[r]);
      u64 k = ((u64)__float_as_uint(D) << 16) | (u32)idx;
      atomicMin(&best_s[r], k);
    }
  }
  if (nOvf) __syncthreads();

  if (tid < 32) {
    const int r = tid;
    const u64 k = best_s[r];
    const int bidx = (int)(k & 0xFFFF);
    widx_s[r] = bidx;
    out_idx[n0 + r] = (float)bidx;
    D_s[r] = __uint_as_float((u32)(k >> 16));
  }
  __syncthreads();
  if (tid == 0) {
    float s = 0.f;
    for (int r = 0; r < 32; ++r) s += D_s[r];
    atomicAdd(loss_ws, s);
    __threadfence();
    int t = atomicAdd(ctr, 1);
    if (t == 511)
      *out_loss = atomicAdd(loss_ws, 0.0f) * (1.25f / 4194304.0f);
  }

  {
    const int col = tid & 255, hi = tid >> 8;
#pragma unroll
    for (int wi0 = 0; wi0 < 16; ++wi0) {
      const int wi = wi0 * 2 + hi;
      zrows[wi][col] = emb[(size_t)widx_s[wi] * 256 + col];
    }
  }
  __syncthreads();
  {
    const int w = tid & 31, c0 = (tid >> 5) & 7, hi = tid >> 8;
    float* dst = z_st + (size_t)b * 262144 + h * 32 + w;
#pragma unroll
    for (int cj = 0; cj < 16; ++cj) {
      int c = c0 + (cj * 2 + hi) * 8;
      dst[(size_t)c * 1024] = zrows[w][c];
    }
  }
}

extern "C" void kernel_launch(void* const* d_in, const int* in_sizes, int n_in,
                              void* d_out, int out_size, void* d_ws, size_t ws_size,
                              hipStream_t stream) {
  const float* z = (const float*)d_in[0];     // fp32 [16,256,32,32]
  const float* emb = (const float*)d_in[1];   // fp32 [8192,256]
  char* ws = (char*)d_ws;
  char* zb8 = ws + OFF_ZB8;
  char* eb8 = ws + OFF_EB8;
  int* g_cnt = (int*)(ws + OFF_CNT);
  char* cand = ws + OFF_CAND;
  float* loss_ws = (float*)(ws + OFF_LOSS);
  int* ctr = (int*)(ws + OFF_CTR);
  float* out = (float*)d_out;
  float* out_loss = out + ZN;       // output 1
  float* out_idx = out + ZN + 1;    // output 2

  prep_kernel<<<1024, 256, 0, stream>>>(z, emb, zb8, eb8, g_cnt, loss_ws, ctr);
  scores_kernel<<<1024, 512, 0, stream>>>(zb8, eb8, g_cnt, cand);
  rescore_fin_kernel<<<512, 512, 0, stream>>>(z, emb, g_cnt, cand, loss_ws, ctr,
                                              out, out_loss, out_idx);
}

// Round 9
// 199.499 us; speedup vs baseline: 1.3660x; 1.0880x over previous
//
#include <hip/hip_runtime.h>

typedef __attribute__((ext_vector_type(4))) int i32x4;
typedef unsigned short u16;
typedef unsigned char u8;
typedef unsigned int u32;
typedef unsigned long long u64;

static constexpr int NROW = 16384;   // b*h*w
static constexpr int NCODE = 8192;
static constexpr int ZN = 4194304;   // b*c*h*w
static constexpr int MARGIN_I = 4200;   // 2.5e-4 * 2^24

// Per-row candidate slots now live in LDS:
//   16 groups (half*8 + wave) x GCAP + OCAP overflow slots = 120 u16 per row.
static constexpr int GCAP = 6;
static constexpr int OCAP = 24;

// workspace layout (bytes)
static constexpr size_t OFF_EB8  = 0;          // i8 granules e  2 MB
static constexpr size_t OFF_LOSS = 2097152;    // float
static constexpr size_t OFF_CTR  = 2097156;    // int

__device__ __forceinline__ char q8(float v, float s) {
  int x = __float2int_rn(v * s);
  x = x < -128 ? -128 : (x > 127 ? 127 : x);
  return (char)x;
}

// max over each 16-lane row via DPP row_ror (VALU pipe, no LDS traffic)
__device__ __forceinline__ int rowmax16(int m) {
  m = max(m, __builtin_amdgcn_update_dpp(m, m, 0x121, 0xf, 0xf, false)); // ror:1
  m = max(m, __builtin_amdgcn_update_dpp(m, m, 0x122, 0xf, 0xf, false)); // ror:2
  m = max(m, __builtin_amdgcn_update_dpp(m, m, 0x124, 0xf, 0xf, false)); // ror:4
  m = max(m, __builtin_amdgcn_update_dpp(m, m, 0x128, 0xf, 0xf, false)); // ror:8
  return m;
}

// ---- numpy fp32 replica (verified rounds 4-9; no FMA contraction) ----
// zr must be 16B-aligned; scalars re-sourced from float4 components in the
// EXACT same operation order as the scalar version (bit-identical).
#pragma clang fp contract(off)
__device__ float np_dist(const float* zr, const float* __restrict__ er, float A) {
  const float4* e4 = (const float4*)er;
  const float4* z4 = (const float4*)zr;
  float s0 = 0.f, s1 = 0.f, s2 = 0.f, s3 = 0.f;
#pragma unroll 4
  for (int i16 = 0; i16 < 16; ++i16) {
    float4 ea = e4[i16 * 4 + 0], eb = e4[i16 * 4 + 1];
    float4 ec = e4[i16 * 4 + 2], ed = e4[i16 * 4 + 3];
    float4 za = z4[i16 * 4 + 0], zb = z4[i16 * 4 + 1];
    float4 zc = z4[i16 * 4 + 2], zd = z4[i16 * 4 + 3];
    s0 = __fadd_rn(__fmul_rn(za.x, ea.x),
         __fadd_rn(__fmul_rn(zb.x, eb.x),
         __fadd_rn(__fmul_rn(zc.x, ec.x),
         __fadd_rn(__fmul_rn(zd.x, ed.x), s0))));
    s1 = __fadd_rn(__fmul_rn(za.y, ea.y),
         __fadd_rn(__fmul_rn(zb.y, eb.y),
         __fadd_rn(__fmul_rn(zc.y, ec.y),
         __fadd_rn(__fmul_rn(zd.y, ed.y), s1))));
    s2 = __fadd_rn(__fmul_rn(za.z, ea.z),
         __fadd_rn(__fmul_rn(zb.z, eb.z),
         __fadd_rn(__fmul_rn(zc.z, ec.z),
         __fadd_rn(__fmul_rn(zd.z, ed.z), s2))));
    s3 = __fadd_rn(__fmul_rn(za.w, ea.w),
         __fadd_rn(__fmul_rn(zb.w, eb.w),
         __fadd_rn(__fmul_rn(zc.w, ec.w),
         __fadd_rn(__fmul_rn(zd.w, ed.w), s3))));
  }
  float C = __fadd_rn(__fadd_rn(s0, s1), __fadd_rn(s2, s3));
  return __fadd_rn(A, -(2.0f * C));
}

// A = np pairwise-sum replica of ||z||^2 (verified rounds 4-9).
__device__ float np_rowA(const float* zrow, int lane, volatile float* red) {
  if (lane < 16) {
    const int half = lane >> 3, jj = lane & 7;
    const float* p = zrow + half * 128 + jj;
    float acc = __fmul_rn(p[0], p[0]);
    for (int i = 8; i < 128; i += 8) acc = __fadd_rn(acc, __fmul_rn(p[i], p[i]));
    red[lane] = acc;
  }
  float h0 = __fadd_rn(__fadd_rn(__fadd_rn(red[0], red[1]), __fadd_rn(red[2], red[3])),
                       __fadd_rn(__fadd_rn(red[4], red[5]), __fadd_rn(red[6], red[7])));
  float h1 = __fadd_rn(__fadd_rn(__fadd_rn(red[8], red[9]), __fadd_rn(red[10], red[11])),
                       __fadd_rn(__fadd_rn(red[12], red[13]), __fadd_rn(red[14], red[15])));
  return __fadd_rn(h0, h1);
}
#pragma clang fp contract(fast)

// ---- kernel 1: e-prep — e -> i8 lane-ordered granules; zero loss/ctr ----
__global__ __launch_bounds__(256) void eprep_kernel(const float* __restrict__ e,
                                                    char* __restrict__ eb8,
                                                    float* __restrict__ loss_ws,
                                                    int* __restrict__ ctr) {
  const int G = blockIdx.x * 256 + threadIdx.x;   // 0..131071
  if (G == 0) { *loss_ws = 0.f; *ctr = 0; }
  const int tile = G >> 8, r = G & 255;
  const int kb = r >> 6, lane = r & 63;
  const int l4 = lane >> 4, l15 = lane & 15;
  const float* s = e + (size_t)(tile * 16 + l15) * 256 + kb * 64 + l4 * 16;
  union { char c[16]; i32x4 v; } u;
#pragma unroll
  for (int j = 0; j < 16; ++j) u.c[j] = q8(s[j], 1048576.0f);
  *(i32x4*)(eb8 + (size_t)G * 16) = u.v;
}

// ---- kernel 2: fused scores + rescore ----
// One block = 32 rows x ALL 8192 codes (64 chunks). z loaded fp32 to LDS once
// (it's needed for rescore anyway), A-fragments quantized in-block with the
// exact prep math. Candidates pushed to LDS slots (no global round-trip, no
// g_cnt). Then the verified rescore phase runs in-place.
__global__ __launch_bounds__(512, 2) void fused_kernel(const float* __restrict__ z,
                                                       const char* __restrict__ eb8,
                                                       const float* __restrict__ emb,
                                                       float* __restrict__ loss_ws,
                                                       int* __restrict__ ctr,
                                                       float* __restrict__ z_st,
                                                       float* __restrict__ out_loss,
                                                       float* __restrict__ out_idx) {
  __shared__ float zrows[32][260];
  __shared__ int s_rm[32];
  __shared__ u32 s_cnt[32][16];
  __shared__ u32 s_ovf[32];
  __shared__ u16 s_slots[32][120];   // 16*GCAP=96 group slots + OCAP overflow
  __shared__ float red_s[8][16];
  __shared__ float A_s[32], D_s[32];
  __shared__ u64 best_s[32];
  __shared__ int widx_s[32], starts[33], ovf_list[32], rowtot[32];
  __shared__ int nP, nOvf;
  __shared__ u8 cnts8[32][17];
  __shared__ u16 grpoff[32][17];
  __shared__ u8 prow[32 * 120];
  __shared__ u16 pidx[32 * 120];

  const int bh = blockIdx.x;
  const int b = bh >> 5, h = bh & 31;
  const int n0 = bh * 32;
  const int tid = threadIdx.x;
  const int wave = tid >> 6, lane = tid & 63;
  const int l15 = lane & 15, l4 = lane >> 4;

  // ---- prologue: z rows fp32 -> LDS (transposed), init LDS state ----
  {
    const float* src = z + (size_t)b * 262144 + h * 32;
    const int w = tid & 31, c16 = tid >> 5;   // c16: 0..15
#pragma unroll
    for (int c0 = 0; c0 < 256; c0 += 16) {
      int c = c0 + c16;
      zrows[w][c] = src[(size_t)c * 1024 + w];
    }
  }
  if (tid < 32) { s_rm[tid] = INT_MIN; s_ovf[tid] = 0; best_s[tid] = ~0ull; }
  s_cnt[tid >> 4][tid & 15] = 0;   // 512 threads cover [32][16]
  __syncthreads();

  // ---- A fragments: quantize from zrows with prep's exact math/layout ----
  // lane holds row = rt*16 + l15, k-bytes c = kb*64 + l4*16 + j.
  i32x4 a[2][4];
#pragma unroll
  for (int rt = 0; rt < 2; ++rt) {
    const float* zr = zrows[rt * 16 + l15];
#pragma unroll
    for (int kb = 0; kb < 4; ++kb) {
      const int c0 = kb * 64 + l4 * 16;
      union { char c[16]; i32x4 v; } u;
#pragma unroll
      for (int j = 0; j < 16; ++j) u.c[j] = q8(zr[c0 + j], 16.0f);
      a[rt][kb] = u.v;
    }
  }

  const i32x4* ebase = (const i32x4*)eb8;
  int lmax[2][4];

#define COMPUTE(CH, ACC)                                                          \
  i32x4 ACC[2] = {{0,0,0,0},{0,0,0,0}};                                           \
  {                                                                               \
    const i32x4* bt = ebase + (size_t)((CH) * 8 + wave) * 256;                    \
    i32x4 bf0 = bt[lane], bf1 = bt[64 + lane], bf2 = bt[128 + lane], bf3 = bt[192 + lane]; \
    _Pragma("unroll")                                                             \
    for (int rt = 0; rt < 2; ++rt) {                                              \
      ACC[rt] = __builtin_amdgcn_mfma_i32_16x16x64_i8(a[rt][0], bf0, ACC[rt], 0, 0, 0); \
      ACC[rt] = __builtin_amdgcn_mfma_i32_16x16x64_i8(a[rt][1], bf1, ACC[rt], 0, 0, 0); \
      ACC[rt] = __builtin_amdgcn_mfma_i32_16x16x64_i8(a[rt][2], bf2, ACC[rt], 0, 0, 0); \
      ACC[rt] = __builtin_amdgcn_mfma_i32_16x16x64_i8(a[rt][3], bf3, ACC[rt], 0, 0, 0); \
    }                                                                             \
  }

// s_rm is monotone (atomicMax only) -> relaxed barrier; LDS-only drain.
#define SYNC_THR()                                                               \
  {                                                                              \
    _Pragma("unroll")                                                            \
    for (int rt = 0; rt < 2; ++rt)                                               \
      _Pragma("unroll")                                                          \
      for (int r = 0; r < 4; ++r) {                                              \
        int m = rowmax16(lmax[rt][r]);                                           \
        if (l15 == 0) atomicMax(&s_rm[rt * 16 + l4 * 4 + r], m);                 \
      }                                                                          \
    asm volatile("s_waitcnt lgkmcnt(0)\n\ts_barrier" ::: "memory");              \
    _Pragma("unroll")                                                            \
    for (int rt = 0; rt < 2; ++rt)                                               \
      _Pragma("unroll")                                                          \
      for (int r = 0; r < 4; ++r)                                                \
        lmax[rt][r] = max(lmax[rt][r], s_rm[rt * 16 + l4 * 4 + r]);              \
  }

  // seed: chunks 0..1, maxes only — warms the threshold
#pragma unroll 1
  for (int ch = 0; ch < 2; ++ch) {
    COMPUTE(ch, acc);
    if (ch == 0) {
#pragma unroll
      for (int rt = 0; rt < 2; ++rt)
#pragma unroll
        for (int r = 0; r < 4; ++r) lmax[rt][r] = acc[rt][r];
    } else {
#pragma unroll
      for (int rt = 0; rt < 2; ++rt)
#pragma unroll
        for (int r = 0; r < 4; ++r) lmax[rt][r] = max(lmax[rt][r], acc[rt][r]);
    }
  }
  SYNC_THR();

  // main: 64 chunks cover all 8192 codes; group = (half)*8 + wave
#pragma unroll 1
  for (int ch = 0; ch < 64; ++ch) {
    COMPUTE(ch, acc);
    const int grp = (ch >> 5) * 8 + wave;
#pragma unroll
    for (int rt = 0; rt < 2; ++rt)
#pragma unroll
      for (int r = 0; r < 4; ++r) {
        const int v = acc[rt][r];
        const bool p = v > lmax[rt][r] - MARGIN_I;   // superset of final set
        if (__any(p)) {                              // scalar skip: pushes are rare
          if (p) {
            const int rl = rt * 16 + l4 * 4 + r;
            u32 q = atomicAdd(&s_cnt[rl][grp], 1u);  // LDS atomic
            if (q < GCAP) {
              s_slots[rl][grp * GCAP + q] = (u16)(ch * 128 + wave * 16 + l15);
            } else {                                 // rare spill tier (LDS)
              u32 o = atomicAdd(&s_ovf[rl], 1u);
              if (o < OCAP)
                s_slots[rl][96 + o] = (u16)(ch * 128 + wave * 16 + l15);
            }
          }
        }
        lmax[rt][r] = max(lmax[rt][r], v);
      }
    if ((ch & 3) == 3 && ch != 63) SYNC_THR();
  }
#undef COMPUTE
#undef SYNC_THR
  __syncthreads();   // all pushes visible

  // ---- rescore phase (verified structure, sourced from LDS) ----
  for (int j = 0; j < 4; ++j) {
    const int r = wave * 4 + j;
    float A = np_rowA(zrows[r], lane, red_s[wave]);
    if (lane == 0) A_s[r] = A;
  }
  if (tid < 32) {
    const int r = tid;
    int tot = 0;
#pragma unroll
    for (int k = 0; k < 16; ++k) {
      int c = (int)s_cnt[r][k];
      int cc = c > GCAP ? GCAP : c;
      cnts8[r][k] = (u8)cc;
      grpoff[r][k] = (u16)tot;
      tot += cc;
    }
    const int ov = (int)s_ovf[r];
    const int oc = ov > OCAP ? OCAP : ov;
    cnts8[r][16] = (u8)oc;
    grpoff[r][16] = (u16)tot;
    tot += oc;
    rowtot[r] = (ov > OCAP) ? 0 : tot;   // 0 -> block-wide full-scan fallback
  }
  __syncthreads();
  if (tid == 0) {
    int acc = 0, no = 0;
    for (int r = 0; r < 32; ++r) {
      starts[r] = acc;
      acc += rowtot[r];
      if (rowtot[r] == 0) ovf_list[no++] = r;
    }
    starts[32] = acc; nP = acc; nOvf = no;
  }
  __syncthreads();
  {
    const int r = tid >> 4, g = tid & 15;   // 512 threads cover [32][16]
    if (rowtot[r]) {
      const int c = cnts8[r][g];
      const int base = starts[r] + grpoff[r][g];
      const int sb = g * GCAP;
      for (int j = 0; j < c; ++j) {
        prow[base + j] = (u8)r;
        pidx[base + j] = s_slots[r][sb + j];
      }
    }
  }
  if (tid < 32) {
    const int r = tid;
    if (rowtot[r]) {
      const int c = cnts8[r][16];
      const int base = starts[r] + grpoff[r][16];
      for (int j = 0; j < c; ++j) {
        prow[base + j] = (u8)r;
        pidx[base + j] = s_slots[r][96 + j];
      }
    }
  }
  __syncthreads();

  const int P = nP;
  for (int p = tid; p < P; p += 512) {
    const int r = prow[p], idx = (int)pidx[p];
    float D = np_dist(zrows[r], emb + (size_t)idx * 256, A_s[r]);
    u64 key = ((u64)__float_as_uint(D) << 16) | (u32)idx;
    atomicMin(&best_s[r], key);
  }
  __syncthreads();

  // overflow fallback (spill>OCAP, ~never): block-wide scan
  for (int i = 0; i < nOvf; ++i) {
    const int r = ovf_list[i];
    for (int idx = tid; idx < NCODE; idx += 512) {
      float D = np_dist(zrows[r], emb + (size_t)idx * 256, A_s[r]);
      u64 k = ((u64)__float_as_uint(D) << 16) | (u32)idx;
      atomicMin(&best_s[r], k);
    }
  }
  if (nOvf) __syncthreads();

  if (tid < 32) {
    const int r = tid;
    const u64 k = best_s[r];
    const int bidx = (int)(k & 0xFFFF);
    widx_s[r] = bidx;
    out_idx[n0 + r] = (float)bidx;
    D_s[r] = __uint_as_float((u32)(k >> 16));
  }
  __syncthreads();
  if (tid == 0) {
    float s = 0.f;
    for (int r = 0; r < 32; ++r) s += D_s[r];
    atomicAdd(loss_ws, s);
    __threadfence();
    int t = atomicAdd(ctr, 1);
    if (t == 511)
      *out_loss = atomicAdd(loss_ws, 0.0f) * (1.25f / 4194304.0f);
  }

  {
    const int col = tid & 255, hi = tid >> 8;
#pragma unroll
    for (int wi0 = 0; wi0 < 16; ++wi0) {
      const int wi = wi0 * 2 + hi;
      zrows[wi][col] = emb[(size_t)widx_s[wi] * 256 + col];
    }
  }
  __syncthreads();
  {
    const int w = tid & 31, c0 = (tid >> 5) & 7, hi = tid >> 8;
    float* dst = z_st + (size_t)b * 262144 + h * 32 + w;
#pragma unroll
    for (int cj = 0; cj < 16; ++cj) {
      int c = c0 + (cj * 2 + hi) * 8;
      dst[(size_t)c * 1024] = zrows[w][c];
    }
  }
}

extern "C" void kernel_launch(void* const* d_in, const int* in_sizes, int n_in,
                              void* d_out, int out_size, void* d_ws, size_t ws_size,
                              hipStream_t stream) {
  const float* z = (const float*)d_in[0];     // fp32 [16,256,32,32]
  const float* emb = (const float*)d_in[1];   // fp32 [8192,256]
  char* ws = (char*)d_ws;
  char* eb8 = ws + OFF_EB8;
  float* loss_ws = (float*)(ws + OFF_LOSS);
  int* ctr = (int*)(ws + OFF_CTR);
  float* out = (float*)d_out;
  float* out_loss = out + ZN;       // output 1
  float* out_idx = out + ZN + 1;    // output 2

  eprep_kernel<<<512, 256, 0, stream>>>(emb, eb8, loss_ws, ctr);
  fused_kernel<<<512, 512, 0, stream>>>(z, eb8, emb, loss_ws, ctr,
                                        out, out_loss, out_idx);
}

// Round 10
// 189.044 us; speedup vs baseline: 1.4416x; 1.0553x over previous
//
#include <hip/hip_runtime.h>

typedef __attribute__((ext_vector_type(4))) int i32x4;
typedef unsigned short u16;
typedef unsigned char u8;
typedef unsigned int u32;
typedef unsigned long long u64;

static constexpr int NROW = 16384;   // b*h*w
static constexpr int NCODE = 8192;
static constexpr int ZN = 4194304;   // b*c*h*w
static constexpr int MARGIN_I = 4200;   // 2.5e-4 * 2^24

// Per-row candidate slots in LDS: 16 groups x GCAP + OCAP overflow = 120 u16.
static constexpr int GCAP = 6;
static constexpr int OCAP = 24;

// workspace layout (bytes)
static constexpr size_t OFF_EB8  = 0;          // i8 granules e  2 MB
static constexpr size_t OFF_LOSS = 2097152;    // float
static constexpr size_t OFF_CTR  = 2097156;    // int

__device__ __forceinline__ char q8(float v, float s) {
  int x = __float2int_rn(v * s);
  x = x < -128 ? -128 : (x > 127 ? 127 : x);
  return (char)x;
}

// max over each 16-lane row via DPP row_ror (VALU pipe, no LDS traffic)
__device__ __forceinline__ int rowmax16(int m) {
  m = max(m, __builtin_amdgcn_update_dpp(m, m, 0x121, 0xf, 0xf, false)); // ror:1
  m = max(m, __builtin_amdgcn_update_dpp(m, m, 0x122, 0xf, 0xf, false)); // ror:2
  m = max(m, __builtin_amdgcn_update_dpp(m, m, 0x124, 0xf, 0xf, false)); // ror:4
  m = max(m, __builtin_amdgcn_update_dpp(m, m, 0x128, 0xf, 0xf, false)); // ror:8
  return m;
}

// ---- numpy fp32 replica (verified rounds 4-9; no FMA contraction) ----
// zr must be 16B-aligned; scalars re-sourced from float4 components in the
// EXACT same operation order as the scalar version (bit-identical).
#pragma clang fp contract(off)
__device__ float np_dist(const float* zr, const float* __restrict__ er, float A) {
  const float4* e4 = (const float4*)er;
  const float4* z4 = (const float4*)zr;
  float s0 = 0.f, s1 = 0.f, s2 = 0.f, s3 = 0.f;
#pragma unroll 4
  for (int i16 = 0; i16 < 16; ++i16) {
    float4 ea = e4[i16 * 4 + 0], eb = e4[i16 * 4 + 1];
    float4 ec = e4[i16 * 4 + 2], ed = e4[i16 * 4 + 3];
    float4 za = z4[i16 * 4 + 0], zb = z4[i16 * 4 + 1];
    float4 zc = z4[i16 * 4 + 2], zd = z4[i16 * 4 + 3];
    s0 = __fadd_rn(__fmul_rn(za.x, ea.x),
         __fadd_rn(__fmul_rn(zb.x, eb.x),
         __fadd_rn(__fmul_rn(zc.x, ec.x),
         __fadd_rn(__fmul_rn(zd.x, ed.x), s0))));
    s1 = __fadd_rn(__fmul_rn(za.y, ea.y),
         __fadd_rn(__fmul_rn(zb.y, eb.y),
         __fadd_rn(__fmul_rn(zc.y, ec.y),
         __fadd_rn(__fmul_rn(zd.y, ed.y), s1))));
    s2 = __fadd_rn(__fmul_rn(za.z, ea.z),
         __fadd_rn(__fmul_rn(zb.z, eb.z),
         __fadd_rn(__fmul_rn(zc.z, ec.z),
         __fadd_rn(__fmul_rn(zd.z, ed.z), s2))));
    s3 = __fadd_rn(__fmul_rn(za.w, ea.w),
         __fadd_rn(__fmul_rn(zb.w, eb.w),
         __fadd_rn(__fmul_rn(zc.w, ec.w),
         __fadd_rn(__fmul_rn(zd.w, ed.w), s3))));
  }
  float C = __fadd_rn(__fadd_rn(s0, s1), __fadd_rn(s2, s3));
  return __fadd_rn(A, -(2.0f * C));
}

// A = np pairwise-sum replica of ||z||^2 (verified rounds 4-9).
__device__ float np_rowA(const float* zrow, int lane, volatile float* red) {
  if (lane < 16) {
    const int half = lane >> 3, jj = lane & 7;
    const float* p = zrow + half * 128 + jj;
    float acc = __fmul_rn(p[0], p[0]);
    for (int i = 8; i < 128; i += 8) acc = __fadd_rn(acc, __fmul_rn(p[i], p[i]));
    red[lane] = acc;
  }
  float h0 = __fadd_rn(__fadd_rn(__fadd_rn(red[0], red[1]), __fadd_rn(red[2], red[3])),
                       __fadd_rn(__fadd_rn(red[4], red[5]), __fadd_rn(red[6], red[7])));
  float h1 = __fadd_rn(__fadd_rn(__fadd_rn(red[8], red[9]), __fadd_rn(red[10], red[11])),
                       __fadd_rn(__fadd_rn(red[12], red[13]), __fadd_rn(red[14], red[15])));
  return __fadd_rn(h0, h1);
}
#pragma clang fp contract(fast)

// ---- kernel 1: e-prep — e -> i8 lane-ordered granules; zero loss/ctr ----
__global__ __launch_bounds__(256) void eprep_kernel(const float* __restrict__ e,
                                                    char* __restrict__ eb8,
                                                    float* __restrict__ loss_ws,
                                                    int* __restrict__ ctr) {
  const int G = blockIdx.x * 256 + threadIdx.x;   // 0..131071
  if (G == 0) { *loss_ws = 0.f; *ctr = 0; }
  const int tile = G >> 8, r = G & 255;
  const int kb = r >> 6, lane = r & 63;
  const int l4 = lane >> 4, l15 = lane & 15;
  const float* s = e + (size_t)(tile * 16 + l15) * 256 + kb * 64 + l4 * 16;
  union { char c[16]; i32x4 v; } u;
#pragma unroll
  for (int j = 0; j < 16; ++j) u.c[j] = q8(s[j], 1048576.0f);
  *(i32x4*)(eb8 + (size_t)G * 16) = u.v;
}

// ---- kernel 2: fused scores + rescore ----
// vs round 9: (a) prow[] removed (binary search over starts[] instead) ->
// LDS 58368 -> ~54272 B -> 3 blocks/CU (occupancy cap 16 -> 24 waves/CU);
// (b) depth-1 B-fragment prefetch in the chunk loop (52 of 128 VGPRs used --
// the round-3 pipeline attempt finally gets the register budget it needed).
__global__ __launch_bounds__(512, 2) void fused_kernel(const float* __restrict__ z,
                                                       const char* __restrict__ eb8,
                                                       const float* __restrict__ emb,
                                                       float* __restrict__ loss_ws,
                                                       int* __restrict__ ctr,
                                                       float* __restrict__ z_st,
                                                       float* __restrict__ out_loss,
                                                       float* __restrict__ out_idx) {
  __shared__ float zrows[32][260];
  __shared__ int s_rm[32];
  __shared__ u32 s_cnt[32][16];
  __shared__ u32 s_ovf[32];
  __shared__ u16 s_slots[32][120];   // 16*GCAP=96 group slots + OCAP overflow
  __shared__ float red_s[8][16];
  __shared__ float A_s[32], D_s[32];
  __shared__ u64 best_s[32];
  __shared__ int widx_s[32], starts[33], ovf_list[32], rowtot[32];
  __shared__ int nP, nOvf;
  __shared__ u8 cnts8[32][17];
  __shared__ u16 grpoff[32][17];
  __shared__ u16 pidx[32 * 120];

  const int bh = blockIdx.x;
  const int b = bh >> 5, h = bh & 31;
  const int n0 = bh * 32;
  const int tid = threadIdx.x;
  const int wave = tid >> 6, lane = tid & 63;
  const int l15 = lane & 15, l4 = lane >> 4;

  // ---- prologue: z rows fp32 -> LDS (transposed), init LDS state ----
  {
    const float* src = z + (size_t)b * 262144 + h * 32;
    const int w = tid & 31, c16 = tid >> 5;   // c16: 0..15
#pragma unroll
    for (int c0 = 0; c0 < 256; c0 += 16) {
      int c = c0 + c16;
      zrows[w][c] = src[(size_t)c * 1024 + w];
    }
  }
  if (tid < 32) { s_rm[tid] = INT_MIN; s_ovf[tid] = 0; best_s[tid] = ~0ull; }
  s_cnt[tid >> 4][tid & 15] = 0;   // 512 threads cover [32][16]
  __syncthreads();

  // ---- A fragments: quantize from zrows with prep's exact math/layout ----
  i32x4 a[2][4];
#pragma unroll
  for (int rt = 0; rt < 2; ++rt) {
    const float* zr = zrows[rt * 16 + l15];
#pragma unroll
    for (int kb = 0; kb < 4; ++kb) {
      const int c0 = kb * 64 + l4 * 16;
      union { char c[16]; i32x4 v; } u;
#pragma unroll
      for (int j = 0; j < 16; ++j) u.c[j] = q8(zr[c0 + j], 16.0f);
      a[rt][kb] = u.v;
    }
  }

  const i32x4* ebase = (const i32x4*)eb8;
  int lmax[2][4];

#define LOADB(CH, B0, B1, B2, B3)                                                \
  {                                                                              \
    const i32x4* bt = ebase + (size_t)((CH) * 8 + wave) * 256;                   \
    B0 = bt[lane]; B1 = bt[64 + lane]; B2 = bt[128 + lane]; B3 = bt[192 + lane]; \
  }

#define MFMA8(B0, B1, B2, B3, ACC)                                               \
  _Pragma("unroll")                                                              \
  for (int rt = 0; rt < 2; ++rt) {                                               \
    ACC[rt] = __builtin_amdgcn_mfma_i32_16x16x64_i8(a[rt][0], B0, ACC[rt], 0, 0, 0); \
    ACC[rt] = __builtin_amdgcn_mfma_i32_16x16x64_i8(a[rt][1], B1, ACC[rt], 0, 0, 0); \
    ACC[rt] = __builtin_amdgcn_mfma_i32_16x16x64_i8(a[rt][2], B2, ACC[rt], 0, 0, 0); \
    ACC[rt] = __builtin_amdgcn_mfma_i32_16x16x64_i8(a[rt][3], B3, ACC[rt], 0, 0, 0); \
  }

// s_rm is monotone (atomicMax only) -> relaxed barrier; LDS-only drain so
// in-flight prefetch loads survive the barrier.
#define SYNC_THR()                                                               \
  {                                                                              \
    _Pragma("unroll")                                                            \
    for (int rt = 0; rt < 2; ++rt)                                               \
      _Pragma("unroll")                                                          \
      for (int r = 0; r < 4; ++r) {                                              \
        int m = rowmax16(lmax[rt][r]);                                           \
        if (l15 == 0) atomicMax(&s_rm[rt * 16 + l4 * 4 + r], m);                 \
      }                                                                          \
    asm volatile("s_waitcnt lgkmcnt(0)\n\ts_barrier" ::: "memory");              \
    _Pragma("unroll")                                                            \
    for (int rt = 0; rt < 2; ++rt)                                               \
      _Pragma("unroll")                                                          \
      for (int r = 0; r < 4; ++r)                                                \
        lmax[rt][r] = max(lmax[rt][r], s_rm[rt * 16 + l4 * 4 + r]);              \
  }

  // seed: chunks 0..1, maxes only — warms the threshold
  {
    i32x4 b0, b1, b2, b3;
#pragma unroll 1
    for (int ch = 0; ch < 2; ++ch) {
      LOADB(ch, b0, b1, b2, b3);
      i32x4 acc[2] = {{0,0,0,0},{0,0,0,0}};
      MFMA8(b0, b1, b2, b3, acc);
      if (ch == 0) {
#pragma unroll
        for (int rt = 0; rt < 2; ++rt)
#pragma unroll
          for (int r = 0; r < 4; ++r) lmax[rt][r] = acc[rt][r];
      } else {
#pragma unroll
        for (int rt = 0; rt < 2; ++rt)
#pragma unroll
          for (int r = 0; r < 4; ++r) lmax[rt][r] = max(lmax[rt][r], acc[rt][r]);
      }
    }
  }
  SYNC_THR();

  // main: 64 chunks cover all 8192 codes; depth-1 B prefetch
  {
    i32x4 b0, b1, b2, b3, p0, p1, p2, p3;
    LOADB(0, b0, b1, b2, b3);
#pragma unroll 1
    for (int ch = 0; ch < 64; ++ch) {
      if (ch < 63) LOADB(ch + 1, p0, p1, p2, p3);
      i32x4 acc[2] = {{0,0,0,0},{0,0,0,0}};
      MFMA8(b0, b1, b2, b3, acc);
      const int grp = (ch >> 5) * 8 + wave;
#pragma unroll
      for (int rt = 0; rt < 2; ++rt)
#pragma unroll
        for (int r = 0; r < 4; ++r) {
          const int v = acc[rt][r];
          const bool p = v > lmax[rt][r] - MARGIN_I;   // superset of final set
          if (__any(p)) {                              // scalar skip: pushes rare
            if (p) {
              const int rl = rt * 16 + l4 * 4 + r;
              u32 q = atomicAdd(&s_cnt[rl][grp], 1u);  // LDS atomic
              if (q < GCAP) {
                s_slots[rl][grp * GCAP + q] = (u16)(ch * 128 + wave * 16 + l15);
              } else {                                 // rare spill tier (LDS)
                u32 o = atomicAdd(&s_ovf[rl], 1u);
                if (o < OCAP)
                  s_slots[rl][96 + o] = (u16)(ch * 128 + wave * 16 + l15);
              }
            }
          }
          lmax[rt][r] = max(lmax[rt][r], v);
        }
      if ((ch & 3) == 3 && ch != 63) SYNC_THR();
      b0 = p0; b1 = p1; b2 = p2; b3 = p3;
    }
  }
#undef LOADB
#undef MFMA8
#undef SYNC_THR
  __syncthreads();   // all pushes visible

  // ---- rescore phase (verified structure, sourced from LDS) ----
  for (int j = 0; j < 4; ++j) {
    const int r = wave * 4 + j;
    float A = np_rowA(zrows[r], lane, red_s[wave]);
    if (lane == 0) A_s[r] = A;
  }
  if (tid < 32) {
    const int r = tid;
    int tot = 0;
#pragma unroll
    for (int k = 0; k < 16; ++k) {
      int c = (int)s_cnt[r][k];
      int cc = c > GCAP ? GCAP : c;
      cnts8[r][k] = (u8)cc;
      grpoff[r][k] = (u16)tot;
      tot += cc;
    }
    const int ov = (int)s_ovf[r];
    const int oc = ov > OCAP ? OCAP : ov;
    cnts8[r][16] = (u8)oc;
    grpoff[r][16] = (u16)tot;
    tot += oc;
    rowtot[r] = (ov > OCAP) ? 0 : tot;   // 0 -> block-wide full-scan fallback
  }
  __syncthreads();
  if (tid == 0) {
    int acc = 0, no = 0;
    for (int r = 0; r < 32; ++r) {
      starts[r] = acc;
      acc += rowtot[r];
      if (rowtot[r] == 0) ovf_list[no++] = r;
    }
    starts[32] = acc; nP = acc; nOvf = no;
  }
  __syncthreads();
  {
    const int r = tid >> 4, g = tid & 15;   // 512 threads cover [32][16]
    if (rowtot[r]) {
      const int c = cnts8[r][g];
      const int base = starts[r] + grpoff[r][g];
      const int sb = g * GCAP;
      for (int j = 0; j < c; ++j) pidx[base + j] = s_slots[r][sb + j];
    }
  }
  if (tid < 32) {
    const int r = tid;
    if (rowtot[r]) {
      const int c = cnts8[r][16];
      const int base = starts[r] + grpoff[r][16];
      for (int j = 0; j < c; ++j) pidx[base + j] = s_slots[r][96 + j];
    }
  }
  __syncthreads();

  const int P = nP;
  for (int p = tid; p < P; p += 512) {
    // row lookup: largest r with starts[r] <= p (5-step binary search; rows
    // with empty ranges are skipped automatically since starts[r]==starts[r+1])
    int lo = 0, hi = 32;
#pragma unroll
    for (int s = 0; s < 5; ++s) {
      int mid = (lo + hi) >> 1;
      if (starts[mid] <= p) lo = mid; else hi = mid;
    }
    const int r = lo, idx = (int)pidx[p];
    float D = np_dist(zrows[r], emb + (size_t)idx * 256, A_s[r]);
    u64 key = ((u64)__float_as_uint(D) << 16) | (u32)idx;
    atomicMin(&best_s[r], key);
  }
  __syncthreads();

  // overflow fallback (spill>OCAP, ~never): block-wide scan
  for (int i = 0; i < nOvf; ++i) {
    const int r = ovf_list[i];
    for (int idx = tid; idx < NCODE; idx += 512) {
      float D = np_dist(zrows[r], emb + (size_t)idx * 256, A_s[r]);
      u64 k = ((u64)__float_as_uint(D) << 16) | (u32)idx;
      atomicMin(&best_s[r], k);
    }
  }
  if (nOvf) __syncthreads();

  if (tid < 32) {
    const int r = tid;
    const u64 k = best_s[r];
    const int bidx = (int)(k & 0xFFFF);
    widx_s[r] = bidx;
    out_idx[n0 + r] = (float)bidx;
    D_s[r] = __uint_as_float((u32)(k >> 16));
  }
  __syncthreads();
  if (tid == 0) {
    float s = 0.f;
    for (int r = 0; r < 32; ++r) s += D_s[r];
    atomicAdd(loss_ws, s);
    __threadfence();
    int t = atomicAdd(ctr, 1);
    if (t == 511)
      *out_loss = atomicAdd(loss_ws, 0.0f) * (1.25f / 4194304.0f);
  }

  {
    const int col = tid & 255, hi = tid >> 8;
#pragma unroll
    for (int wi0 = 0; wi0 < 16; ++wi0) {
      const int wi = wi0 * 2 + hi;
      zrows[wi][col] = emb[(size_t)widx_s[wi] * 256 + col];
    }
  }
  __syncthreads();
  {
    const int w = tid & 31, c0 = (tid >> 5) & 7, hi = tid >> 8;
    float* dst = z_st + (size_t)b * 262144 + h * 32 + w;
#pragma unroll
    for (int cj = 0; cj < 16; ++cj) {
      int c = c0 + (cj * 2 + hi) * 8;
      dst[(size_t)c * 1024] = zrows[w][c];
    }
  }
}

extern "C" void kernel_launch(void* const* d_in, const int* in_sizes, int n_in,
                              void* d_out, int out_size, void* d_ws, size_t ws_size,
                              hipStream_t stream) {
  const float* z = (const float*)d_in[0];     // fp32 [16,256,32,32]
  const float* emb = (const float*)d_in[1];   // fp32 [8192,256]
  char* ws = (char*)d_ws;
  char* eb8 = ws + OFF_EB8;
  float* loss_ws = (float*)(ws + OFF_LOSS);
  int* ctr = (int*)(ws + OFF_CTR);
  float* out = (float*)d_out;
  float* out_loss = out + ZN;       // output 1
  float* out_idx = out + ZN + 1;    // output 2

  eprep_kernel<<<512, 256, 0, stream>>>(emb, eb8, loss_ws, ctr);
  fused_kernel<<<512, 512, 0, stream>>>(z, eb8, emb, loss_ws, ctr,
                                        out, out_loss, out_idx);
}